// Round 3
// baseline (611.876 us; speedup 1.0000x reference)
//
#include <hip/hip_runtime.h>

// Problem: nearest = memory[argmax_m cosine(x_row, memory_m)], plus copy of x.
//   x: 65536 x 1024 f32, memory: 40 x 1024 f32, out = [nearest (65536x1024) | x (65536x1024)]
//
// d_ws layout (bytes):
//   [0,   320) : double inv64[40]   (1/max(||mem_m||,eps), f64)
//   [320, 480) : float  inv32[40]
//   [512, 8704): unsigned long long flagbits[1024]  (one bit per x-row, 64 rows/word)

#define DIM 1024
#define NMEM 40

constexpr float TAU = 2.5e-4f;   // normalized top-2 gap below which we re-resolve in f64

// ---------------- Kernel 1: memory-row inverse norms (f32 + f64) ----------------
__global__ __launch_bounds__(64) void k_norms(const float* __restrict__ mem,
                                              double* __restrict__ inv64,
                                              float* __restrict__ inv32) {
  const int m = blockIdx.x;      // 40 blocks, 1 wave each
  const int lane = threadIdx.x;
  const float* __restrict__ row = mem + (size_t)m * DIM;
  double s = 0.0;
#pragma unroll
  for (int i = 0; i < DIM / 64; ++i) {
    double v = (double)row[lane + 64 * i];
    s = fma(v, v, s);
  }
#pragma unroll
  for (int off = 32; off > 0; off >>= 1) s += __shfl_xor(s, off, 64);
  if (lane == 0) {
    double n = sqrt(s);
    n = (n > 1e-8) ? n : 1e-8;
    inv64[m] = 1.0 / n;
    inv32[m] = (float)(1.0 / n);
  }
}

// ---------------- Kernel 2: fused sims + argmax + gather + x-copy ----------------
// Block = 4 waves, 64 x-rows (lane == row). Waves split K: wave w owns chunks
// [8w, 8w+8), each chunk = 32 floats of K. Wave-private LDS staging slice =>
// NO barriers in the main loop (per-wave DS ordering + compiler waitcnts only).
// Each wave accumulates partial acc[40] over its K-quarter via wave-uniform
// s_load_dwordx4 of memory rows; 2-pass LDS reduction merges at the end.
__global__ __launch_bounds__(256) void k_main(const float* __restrict__ x,
                                              const float* __restrict__ mem,
                                              const float* __restrict__ inv32,
                                              float* __restrict__ out_near,
                                              float* __restrict__ out_x,
                                              unsigned long long* __restrict__ flagbits) {
  __shared__ float4 stage[4 * 576];   // 36864 B: wave w owns [576w, 576w+576); 64 rows x (8+1 pad) float4
  __shared__ float mv1[4][64];
  __shared__ float mv2[4][64];
  __shared__ int   mi1[4][64];
  __shared__ float nxs[64];
  __shared__ int   amax[64];

  const int tid  = threadIdx.x;
  const int lane = tid & 63;
  const int w    = __builtin_amdgcn_readfirstlane(tid >> 6);  // uniform wave id
  const int rowbase = blockIdx.x * 64;

  const float4* __restrict__ x4 = (const float4*)x + (size_t)rowbase * (DIM / 4);
  float4* __restrict__ ox4      = (float4*)out_x  + (size_t)rowbase * (DIM / 4);
  const float4* __restrict__ m4 = (const float4*)mem;

  // staging mapping: float4 #f of the 64x8 chunk, f = lane + 64*i -> row rS+8i, slot sS
  const int rS = lane >> 3, sS = lane & 7;
  float4* __restrict__ sw = stage + w * 576;

  float acc[40];
#pragma unroll
  for (int m = 0; m < NMEM; ++m) acc[m] = 0.f;
  float nx = 0.f;                      // partial ||x_row||^2 over this wave's K-quarter

  const int kc0 = w * 8;

  // prologue: stage chunk kc0 (x read once; x-copy written from same registers)
  {
    float4 g[8];
#pragma unroll
    for (int i = 0; i < 8; ++i)
      g[i] = x4[(size_t)(rS + 8 * i) * (DIM / 4) + kc0 * 8 + sS];
#pragma unroll
    for (int i = 0; i < 8; ++i) {
      ox4[(size_t)(rS + 8 * i) * (DIM / 4) + kc0 * 8 + sS] = g[i];
      sw[(rS + 8 * i) * 9 + sS] = g[i];
    }
  }

  for (int c = 0; c < 8; ++c) {
    const int kc = kc0 + c;
    float4 h[8];
    if (c < 7) {                       // next chunk's loads issued before compute
#pragma unroll
      for (int i = 0; i < 8; ++i)
        h[i] = x4[(size_t)(rS + 8 * i) * (DIM / 4) + (kc + 1) * 8 + sS];
    }
#pragma unroll
    for (int k4 = 0; k4 < 8; ++k4) {
      float4 xv = sw[lane * 9 + k4];
      nx = fmaf(xv.x, xv.x, fmaf(xv.y, xv.y, fmaf(xv.z, xv.z, fmaf(xv.w, xv.w, nx))));
      const float4* __restrict__ mp = m4 + kc * 8 + k4;
#pragma unroll
      for (int m = 0; m < NMEM; ++m) {
        float4 mv = mp[(size_t)m * (DIM / 4)];   // uniform: s_load_dwordx4, imm offset
        acc[m] = fmaf(xv.x, mv.x, fmaf(xv.y, mv.y, fmaf(xv.z, mv.z, fmaf(xv.w, mv.w, acc[m]))));
      }
    }
    if (c < 7) {                       // per-wave in-order DS: reads(kc) precede these writes
#pragma unroll
      for (int i = 0; i < 8; ++i) {
        ox4[(size_t)(rS + 8 * i) * (DIM / 4) + (kc + 1) * 8 + sS] = h[i];
        sw[(rS + 8 * i) * 9 + sS] = h[i];
      }
    }
  }

  // ---- cross-wave reduction: acc[40] + nx, 2 passes of 20 m's (red overlays stage) ----
  float* red = (float*)stage;          // red[(w*64 + lane)*24 + j], stride 24 (16B-aligned rows)
  float bv1 = -3.4e38f, bv2 = -3.4e38f;
  int bi1 = 0;
  float nxv = 0.f;
#pragma unroll
  for (int p = 0; p < 2; ++p) {
    __syncthreads();                   // p0: all stage reads done; p1: prev red reads done
    float* rw = red + (w * 64 + lane) * 24;
#pragma unroll
    for (int j = 0; j < 20; j += 4) {
      *(float4*)(rw + j) = make_float4(acc[20 * p + j], acc[20 * p + j + 1],
                                       acc[20 * p + j + 2], acc[20 * p + j + 3]);
    }
    if (p == 1) rw[20] = nx;
    __syncthreads();
    // merge: row = lane; wave w takes m = 20p + 5w + j
#pragma unroll
    for (int j = 0; j < 5; ++j) {
      const int jj = 5 * w + j;
      float s = red[(0 * 64 + lane) * 24 + jj] + red[(1 * 64 + lane) * 24 + jj]
              + red[(2 * 64 + lane) * 24 + jj] + red[(3 * 64 + lane) * 24 + jj];
      const int m = 20 * p + jj;
      float v = s * inv32[m];          // ||x|| factor common to all m -> argmax-invariant
      if (v > bv1) { bv2 = bv1; bv1 = v; bi1 = m; }
      else bv2 = fmaxf(bv2, v);
    }
    if (p == 1 && w == 0) {
      nxv = red[(0 * 64 + lane) * 24 + 20] + red[(1 * 64 + lane) * 24 + 20]
          + red[(2 * 64 + lane) * 24 + 20] + red[(3 * 64 + lane) * 24 + 20];
      nxs[lane] = nxv;
    }
  }
  mv1[w][lane] = bv1; mv2[w][lane] = bv2; mi1[w][lane] = bi1;
  __syncthreads();

  if (w == 0) {
    float b1 = mv1[0][lane], b2 = mv2[0][lane];
    int bi = mi1[0][lane];
#pragma unroll
    for (int g = 1; g < 4; ++g) {
      float a1 = mv1[g][lane], a2 = mv2[g][lane];
      int ai = mi1[g][lane];
      if (a1 > b1) { b2 = fmaxf(b1, a2); b1 = a1; bi = ai; }
      else         { b2 = fmaxf(b2, a1); }
    }
    float gap = (b1 - b2) * rsqrtf(fmaxf(nxs[lane], 1e-30f));  // normalized top-2 gap
    bool flag = !(gap >= TAU);                                  // NaN-safe: NaN -> flagged
    unsigned long long mask = __ballot(flag);
    if (lane == 0) flagbits[blockIdx.x] = mask;                 // all 1024 words written every call
    amax[lane] = bi;
  }
  __syncthreads();

  // gather-copy memory[amax] -> out_near, coalesced (each wave does 16 rows)
  float4* __restrict__ on4 = (float4*)out_near + (size_t)rowbase * (DIM / 4);
#pragma unroll 1
  for (int rr = 0; rr < 16; ++rr) {
    int r = (tid >> 6) * 16 + rr;
    int am = amax[r];
    const float4* __restrict__ src = m4 + (size_t)am * (DIM / 4);
    float4* __restrict__ dst = on4 + (size_t)r * (DIM / 4);
#pragma unroll
    for (int j = 0; j < 4; ++j) dst[lane + 64 * j] = src[lane + 64 * j];
  }
}

// ---------------- Kernel 3: f64 re-resolution of razor-thin rows ----------------
__global__ __launch_bounds__(256) void k_refine(const float* __restrict__ x,
                                                const float* __restrict__ mem,
                                                const double* __restrict__ inv64,
                                                const unsigned long long* __restrict__ flagbits,
                                                float* __restrict__ out_near) {
  unsigned long long mask = flagbits[blockIdx.x];
  if (mask == 0ull) return;                 // uniform; nearly all blocks exit here
  const int tid = threadIdx.x;
  const int lane = tid & 63;
  const int wid = tid >> 6;
  __shared__ double bval[4];
  __shared__ int bidx[4];
  while (mask) {
    int r = __ffsll(mask) - 1;
    mask &= (mask - 1ull);
    int row = blockIdx.x * 64 + r;
    const float* __restrict__ xr = x + (size_t)row * DIM;
    double xd[16];
#pragma unroll
    for (int i = 0; i < 16; ++i) xd[i] = (double)xr[lane + 64 * i];
    double best = -1e300;
    int bi = 0;
    for (int q = 0; q < 10; ++q) {
      int m = wid * 10 + q;
      const float* __restrict__ mr = mem + (size_t)m * DIM;
      double s = 0.0;
#pragma unroll
      for (int i = 0; i < 16; ++i) s = fma(xd[i], (double)mr[lane + 64 * i], s);
#pragma unroll
      for (int off = 32; off > 0; off >>= 1) s += __shfl_xor(s, off, 64);
      double v = s * inv64[m];              // identical (bitwise) across lanes
      if (v > best) { best = v; bi = m; }   // strict > keeps lowest m on ties
    }
    if (lane == 0) { bval[wid] = best; bidx[wid] = bi; }
    __syncthreads();
    double g = bval[0];
    int gi = bidx[0];
#pragma unroll
    for (int gg = 1; gg < 4; ++gg) {
      if (bval[gg] > g) { g = bval[gg]; gi = bidx[gg]; }
    }
    const float4* __restrict__ src = (const float4*)mem + (size_t)gi * (DIM / 4);
    float4* __restrict__ dst = (float4*)out_near + (size_t)row * (DIM / 4);
    dst[tid] = src[tid];                    // 256 x 16B = full row, coalesced
    __syncthreads();                        // LDS reuse guard for next flagged row
  }
}

extern "C" void kernel_launch(void* const* d_in, const int* in_sizes, int n_in,
                              void* d_out, int out_size, void* d_ws, size_t ws_size,
                              hipStream_t stream) {
  const float* x   = (const float*)d_in[0];
  const float* mem = (const float*)d_in[1];
  // d_in[2] = top_k (unused: reference only consumes idx[:,0], i.e. the argmax)

  const int n_rows = in_sizes[0] / DIM;          // 65536
  float* out_near = (float*)d_out;
  float* out_x    = (float*)d_out + (size_t)n_rows * DIM;

  double* inv64 = (double*)d_ws;
  float*  inv32 = (float*)((char*)d_ws + 320);
  unsigned long long* flagbits = (unsigned long long*)((char*)d_ws + 512);

  const int nblocks = n_rows / 64;               // 1024

  hipLaunchKernelGGL(k_norms,  dim3(NMEM),    dim3(64),  0, stream, mem, inv64, inv32);
  hipLaunchKernelGGL(k_main,   dim3(nblocks), dim3(256), 0, stream,
                     x, mem, inv32, out_near, out_x, flagbits);
  hipLaunchKernelGGL(k_refine, dim3(nblocks), dim3(256), 0, stream,
                     x, mem, inv64, flagbits, out_near);
}

// Round 4
// 324.554 us; speedup vs baseline: 1.8853x; 1.8853x over previous
//
#include <hip/hip_runtime.h>

// Problem: nearest = memory[argmax_m cosine(x_row, memory_m)], plus copy of x.
//   x: 65536 x 1024 f32, memory: 40 x 1024 f32, out = [nearest (65536x1024) | x (65536x1024)]
//
// d_ws layout (bytes):
//   [0,   320) : double inv64[40]   (1/max(||mem_m||,eps), f64)
//   [320, 480) : float  inv32[40]
//   [512, 8704): unsigned long long flagbits[1024]  (one bit per x-row, 64 rows/word)

#define DIM 1024
#define NMEM 40

constexpr float TAU = 2.5e-4f;   // normalized top-2 gap below which we re-resolve in f64

// ---------------- Kernel 1: memory-row inverse norms (f32 + f64) ----------------
__global__ __launch_bounds__(64) void k_norms(const float* __restrict__ mem,
                                              double* __restrict__ inv64,
                                              float* __restrict__ inv32) {
  const int m = blockIdx.x;      // 40 blocks, 1 wave each
  const int lane = threadIdx.x;
  const float* __restrict__ row = mem + (size_t)m * DIM;
  double s = 0.0;
#pragma unroll
  for (int i = 0; i < DIM / 64; ++i) {
    double v = (double)row[lane + 64 * i];
    s = fma(v, v, s);
  }
#pragma unroll
  for (int off = 32; off > 0; off >>= 1) s += __shfl_xor(s, off, 64);
  if (lane == 0) {
    double n = sqrt(s);
    n = (n > 1e-8) ? n : 1e-8;
    inv64[m] = 1.0 / n;
    inv32[m] = (float)(1.0 / n);
  }
}

// ---------------- Kernel 2: fused sims + argmax + gather + x-copy ----------------
// R1 structure (empirically best), occupancy-doubled: 8 waves/block, 64 x-rows
// (lane == row), wave w owns memory rows [5w, 5w+5). Two barriers per 32-float
// K-chunk; x-copy store issued in the staging phase so the compute phase covers
// its drain before the next barrier's vmcnt(0). 1024 blocks x 8 waves = 32
// waves/CU (was 16 — the R1 cap).
__global__ __launch_bounds__(512) void k_main(const float* __restrict__ x,
                                              const float* __restrict__ mem,
                                              const float* __restrict__ inv32,
                                              float* __restrict__ out_near,
                                              float* __restrict__ out_x,
                                              unsigned long long* __restrict__ flagbits) {
  __shared__ float4 xt[64 * 9];     // 64 rows x 8 float4 slots, +1 pad (R2-measured: 0 conflicts)
  __shared__ float mv1[8][64];
  __shared__ float mv2[8][64];
  __shared__ int   mi1[8][64];
  __shared__ int   amax[64];

  const int tid  = threadIdx.x;
  const int lane = tid & 63;
  const int w    = __builtin_amdgcn_readfirstlane(tid >> 6); // uniform wave id 0..7
  const int mbase = w * 5;
  const int rowbase = blockIdx.x * 64;

  const float4* __restrict__ x4  = (const float4*)x + (size_t)rowbase * (DIM / 4);
  float4* __restrict__ ox4       = (float4*)out_x  + (size_t)rowbase * (DIM / 4);
  const float4* __restrict__ m4  = (const float4*)mem;

  // staging: 512 threads cover the 64x8 float4 chunk exactly once
  const int rT = tid >> 3, sT = tid & 7;
  const size_t gOff = (size_t)rT * (DIM / 4) + sT;
  const int lT = rT * 9 + sT;

  float acc[5];
#pragma unroll
  for (int q = 0; q < 5; ++q) acc[q] = 0.f;
  float nx = 0.f;   // full ||x_row||^2 (every wave scans all K; wave 0's copy is used)

  for (int kc = 0; kc < DIM / 32; ++kc) {
    __syncthreads();  // previous chunk's LDS reads done before overwrite
    {
      float4 v = x4[gOff + (size_t)kc * 8];
      ox4[gOff + (size_t)kc * 8] = v;   // store early: compute phase covers the drain
      xt[lT] = v;
    }
    __syncthreads();
#pragma unroll
    for (int k4 = 0; k4 < 8; ++k4) {
      float4 xv = xt[lane * 9 + k4];
      nx = fmaf(xv.x, xv.x, fmaf(xv.y, xv.y, fmaf(xv.z, xv.z, fmaf(xv.w, xv.w, nx))));
      const float4* __restrict__ mp = m4 + (size_t)kc * 8 + k4;
#pragma unroll
      for (int q = 0; q < 5; ++q) {
        float4 mv = mp[(size_t)(mbase + q) * (DIM / 4)];   // wave-uniform -> s_load_dwordx4
        acc[q] = fmaf(xv.x, mv.x, fmaf(xv.y, mv.y, fmaf(xv.z, mv.z, fmaf(xv.w, mv.w, acc[q]))));
      }
    }
  }

  // per-lane top-2 over this wave's 5 m's (normalize by memory-row norm here;
  // dividing by ||x|| is a common positive factor -> argmax-invariant)
  float v1 = -3.4e38f, v2 = -3.4e38f;
  int i1 = 0;
#pragma unroll
  for (int q = 0; q < 5; ++q) {
    float v = acc[q] * inv32[mbase + q];
    if (v > v1) { v2 = v1; v1 = v; i1 = mbase + q; }
    else if (v > v2) { v2 = v; }
  }
  mv1[w][lane] = v1; mv2[w][lane] = v2; mi1[w][lane] = i1;
  __syncthreads();

  if (w == 0) {
    float b1 = mv1[0][lane], b2 = mv2[0][lane];
    int bi = mi1[0][lane];
#pragma unroll
    for (int g = 1; g < 8; ++g) {
      float a1 = mv1[g][lane], a2 = mv2[g][lane];
      int ai = mi1[g][lane];
      if (a1 > b1) { b2 = fmaxf(b1, a2); b1 = a1; bi = ai; }  // ascending g => ties keep lower m
      else         { b2 = fmaxf(b2, a1); }
    }
    float gap = (b1 - b2) * rsqrtf(fmaxf(nx, 1e-30f));  // normalized top-2 gap
    bool flag = !(gap >= TAU);                           // NaN-safe: NaN -> flagged
    unsigned long long mask = __ballot(flag);
    if (lane == 0) flagbits[blockIdx.x] = mask;          // all 1024 words written every call
    amax[lane] = bi;
  }
  __syncthreads();

  // gather-copy memory[amax] -> out_near, coalesced (each wave does 8 rows)
  float4* __restrict__ on4 = (float4*)out_near + (size_t)rowbase * (DIM / 4);
#pragma unroll 1
  for (int rr = 0; rr < 8; ++rr) {
    int r = (tid >> 6) * 8 + rr;
    int am = amax[r];
    const float4* __restrict__ src = m4 + (size_t)am * (DIM / 4);
    float4* __restrict__ dst = on4 + (size_t)r * (DIM / 4);
#pragma unroll
    for (int j = 0; j < 4; ++j) dst[lane + 64 * j] = src[lane + 64 * j];
  }
}

// ---------------- Kernel 3: f64 re-resolution of razor-thin rows ----------------
__global__ __launch_bounds__(256) void k_refine(const float* __restrict__ x,
                                                const float* __restrict__ mem,
                                                const double* __restrict__ inv64,
                                                const unsigned long long* __restrict__ flagbits,
                                                float* __restrict__ out_near) {
  unsigned long long mask = flagbits[blockIdx.x];
  if (mask == 0ull) return;                 // uniform; nearly all blocks exit here
  const int tid = threadIdx.x;
  const int lane = tid & 63;
  const int wid = tid >> 6;
  __shared__ double bval[4];
  __shared__ int bidx[4];
  while (mask) {
    int r = __ffsll(mask) - 1;
    mask &= (mask - 1ull);
    int row = blockIdx.x * 64 + r;
    const float* __restrict__ xr = x + (size_t)row * DIM;
    double xd[16];
#pragma unroll
    for (int i = 0; i < 16; ++i) xd[i] = (double)xr[lane + 64 * i];
    double best = -1e300;
    int bi = 0;
    for (int q = 0; q < 10; ++q) {
      int m = wid * 10 + q;
      const float* __restrict__ mr = mem + (size_t)m * DIM;
      double s = 0.0;
#pragma unroll
      for (int i = 0; i < 16; ++i) s = fma(xd[i], (double)mr[lane + 64 * i], s);
#pragma unroll
      for (int off = 32; off > 0; off >>= 1) s += __shfl_xor(s, off, 64);
      double v = s * inv64[m];              // identical (bitwise) across lanes
      if (v > best) { best = v; bi = m; }   // strict > keeps lowest m on ties
    }
    if (lane == 0) { bval[wid] = best; bidx[wid] = bi; }
    __syncthreads();
    double g = bval[0];
    int gi = bidx[0];
#pragma unroll
    for (int gg = 1; gg < 4; ++gg) {
      if (bval[gg] > g) { g = bval[gg]; gi = bidx[gg]; }
    }
    const float4* __restrict__ src = (const float4*)mem + (size_t)gi * (DIM / 4);
    float4* __restrict__ dst = (float4*)out_near + (size_t)row * (DIM / 4);
    dst[tid] = src[tid];                    // 256 x 16B = full row, coalesced
    __syncthreads();                        // LDS reuse guard for next flagged row
  }
}

extern "C" void kernel_launch(void* const* d_in, const int* in_sizes, int n_in,
                              void* d_out, int out_size, void* d_ws, size_t ws_size,
                              hipStream_t stream) {
  const float* x   = (const float*)d_in[0];
  const float* mem = (const float*)d_in[1];
  // d_in[2] = top_k (unused: reference only consumes idx[:,0], i.e. the argmax)

  const int n_rows = in_sizes[0] / DIM;          // 65536
  float* out_near = (float*)d_out;
  float* out_x    = (float*)d_out + (size_t)n_rows * DIM;

  double* inv64 = (double*)d_ws;
  float*  inv32 = (float*)((char*)d_ws + 320);
  unsigned long long* flagbits = (unsigned long long*)((char*)d_ws + 512);

  const int nblocks = n_rows / 64;               // 1024

  hipLaunchKernelGGL(k_norms,  dim3(NMEM),    dim3(64),  0, stream, mem, inv64, inv32);
  hipLaunchKernelGGL(k_main,   dim3(nblocks), dim3(512), 0, stream,
                     x, mem, inv32, out_near, out_x, flagbits);
  hipLaunchKernelGGL(k_refine, dim3(nblocks), dim3(256), 0, stream,
                     x, mem, inv64, flagbits, out_near);
}